// Round 18
// baseline (332.852 us; speedup 1.0000x reference)
//
#include <hip/hip_runtime.h>
#include <hip/hip_bf16.h>

constexpr int BATCH = 32768;
constexpr int KDIM  = 128;    // IN_F
constexpr int NDIM  = 2048;   // OUT_F

using f32x4  = __attribute__((ext_vector_type(4))) float;
using bf16x8 = __attribute__((ext_vector_type(8))) short;

// ---------------------------------------------------------------------------
// Fragment order for mfma_f32_16x16x32_bf16 (verified R2/R3):
//   A (MxK): lane l holds m = l&15,  k(j) = 4*(l>>4) + (j&3) + 16*(j>>2)
//   B (KxN): lane l holds n = l&15,  same k(j)
//   D:       lane l holds col = l&15, row = (l>>4)*4 + reg
// 2-term split: z = (x_hi + x_lo) @ W_hi  (absmax ~8e-3 < 2e-2 threshold)
//
// R18 = R16 champion (203.7us) x 4 tiles per block. The 204-240us plateau is
// HBM duty cycle: each block has only ~256KB of HBM work (~10us) but holds
// its CU ~25us; once the pm/out burst drains the HBM pipe idles until the
// next cold block. Fix: 512 blocks x 4 row-tiles, with R16's pmv[8] register
// rotation extended ACROSS tiles -- chunk-1's gather issues the NEXT tile's
// chunk-0 pm loads, so ~8KB/wave stays in flight through Michelot + stores +
// the next GEMM. Only 2 cold starts per CU instead of 8.
// Lessons kept: no NT stores (R13), no global_load_lds staging (R15),
// no 1024-thr blocks (R5-7), launch_bounds load-bearing (R10).
// ---------------------------------------------------------------------------

__device__ inline void split_bf16(float v, ushort& hi, ushort& lo) {
    __hip_bfloat16 h = __float2bfloat16(v);
    float r = v - __bfloat162float(h);
    __hip_bfloat16 l = __float2bfloat16(r);
    hi = *reinterpret_cast<ushort*>(&h);
    lo = *reinterpret_cast<ushort*>(&l);
}

// W [128][2048] -> Bh[nt=128][kk=4][lane=64][j=8]  (hi only)
__global__ __launch_bounds__(256)
void conv_w_kernel(const float* __restrict__ W, ushort* __restrict__ Bh) {
    int id = blockIdx.x * 256 + threadIdx.x;      // 0 .. 262143
    int j  = id & 7;
    int l  = (id >> 3) & 63;
    int kk = (id >> 9) & 3;
    int nt = id >> 11;
    int k  = kk * 32 + 4 * (l >> 4) + (j & 3) + 16 * (j >> 2);
    int n  = nt * 16 + (l & 15);
    __hip_bfloat16 h = __float2bfloat16(W[k * NDIM + n]);
    Bh[id] = *reinterpret_cast<ushort*>(&h);
}

// x [32768][128] -> A{h,l}[rt=2048][kk=4][lane=64][j=8]
__global__ __launch_bounds__(256)
void conv_x_kernel(const float* __restrict__ x,
                   ushort* __restrict__ Ah, ushort* __restrict__ Al) {
    int id = blockIdx.x * 256 + threadIdx.x;      // 0 .. 4194303
    int j  = id & 7;
    int l  = (id >> 3) & 63;
    int kk = (id >> 9) & 3;
    int rt = id >> 11;
    int k  = kk * 32 + 4 * (l >> 4) + (j & 3) + 16 * (j >> 2);
    int m  = rt * 16 + (l & 15);
    ushort hi, lo;
    split_bf16(x[m * KDIM + k], hi, lo);
    Ah[id] = hi; Al[id] = lo;
}

// ---------------------------------------------------------------------------
// Main: grid 512, 512 thr (8 waves), 4 tiles of 16 rows x 2048 cols each.
// GEMM: wave q -> col tiles q*16+t; acc[t][r] = z[row g*4+r][col q*256+...],
// acc in AGPRs. Two 8-row chunks per tile through 64KB LDS (order staggered);
// wave q owns row (c*8+q): coalesced pm/out, in-register wave-local Michelot.
// pm prefetch pipeline spans tiles: there is ALWAYS a pm row in flight.
// ---------------------------------------------------------------------------
constexpr int GRID  = 512;
constexpr int TILES = BATCH / 16 / GRID;        // 4
constexpr int LDS_BYTES = 8 * NDIM * 4;         // 65536 B

__global__ __launch_bounds__(512, 2)
void mfma_sparsemax_kernel(const ushort* __restrict__ Ah, const ushort* __restrict__ Al,
                           const ushort* __restrict__ Bh,
                           const float* __restrict__ pm, float* __restrict__ out) {
    extern __shared__ float zs[];               // [8][2048]

    const int tid = threadIdx.x;
    const int l   = tid & 63;
    const int q   = tid >> 6;                   // wave id 0..7
    const int g   = l >> 4;
    const int c0  = blockIdx.x & 1;             // chunk-order stagger bit

    const bf16x8* A8h = reinterpret_cast<const bf16x8*>(Ah);
    const bf16x8* A8l = reinterpret_cast<const bf16x8*>(Al);
    const bf16x8* B8h = reinterpret_cast<const bf16x8*>(Bh);

    // ---- entry prefetch: pm row for tile 0, first-processed chunk ----
    f32x4 pmv[8];
    {
        const f32x4* pmrow = reinterpret_cast<const f32x4*>(
            pm + ((long)(blockIdx.x * TILES) * 16 + c0 * 8 + q) * NDIM);
        #pragma unroll
        for (int j = 0; j < 8; ++j) pmv[j] = pmrow[j * 64 + l];
    }

    for (int ti = 0; ti < TILES; ++ti) {
        const int rt = blockIdx.x * TILES + ti; // row-tile (16 rows)

        // ---- A fragments (16 rows) ----
        bf16x8 ah[4], al[4];
        #pragma unroll
        for (int kk = 0; kk < 4; ++kk) {
            ah[kk] = A8h[(rt * 4 + kk) * 64 + l];
            al[kk] = A8l[(rt * 4 + kk) * 64 + l];
        }

        // ---- GEMM: wave q -> col tiles nt = q*16+t (pm loads in flight) ----
        f32x4 acc[16];
        #pragma unroll
        for (int t = 0; t < 16; ++t) {
            const int nt = q * 16 + t;
            f32x4 c = {0.f, 0.f, 0.f, 0.f};
            #pragma unroll
            for (int kk = 0; kk < 4; ++kk) {
                bf16x8 b = B8h[(nt * 4 + kk) * 64 + l];
                c = __builtin_amdgcn_mfma_f32_16x16x32_bf16(ah[kk], b, c, 0, 0, 0);
                c = __builtin_amdgcn_mfma_f32_16x16x32_bf16(al[kk], b, c, 0, 0, 0);
            }
            acc[t] = c;
        }

        // ---- two 8-row chunks through LDS, block-staggered order ----
        #pragma unroll
        for (int cc = 0; cc < 2; ++cc) {
            const int c = cc ^ c0;              // this block's chunk order
            __syncthreads();                    // zs free (prev chunk consumed)

            // scatter: g-groups 2c,2c+1 hold chunk c's rows
            if ((g >> 1) == c) {
                #pragma unroll
                for (int t = 0; t < 16; ++t)
                    #pragma unroll
                    for (int r = 0; r < 4; ++r)
                        zs[((g & 1) * 4 + r) * NDIM + q * 256 + t * 16 + (l & 15)] = acc[t][r];
            }

            __syncthreads();                    // zs ready

            // gather my row, gate by (prefetched) pm
            const long grow = (long)rt * 16 + c * 8 + q;
            const f32x4* zrow = reinterpret_cast<const f32x4*>(zs + q * NDIM);
            float zv[32];
            #pragma unroll
            for (int j = 0; j < 8; ++j) {
                f32x4 v = zrow[j * 64 + l];
                zv[j * 4 + 0] = v.x * pmv[j].x;
                zv[j * 4 + 1] = v.y * pmv[j].y;
                zv[j * 4 + 2] = v.z * pmv[j].z;
                zv[j * 4 + 3] = v.w * pmv[j].w;
            }

            // refill pm pipeline: next chunk (cc==0) or next tile (cc==1)
            if (cc == 0) {
                const f32x4* pmrow2 = reinterpret_cast<const f32x4*>(
                    pm + ((long)rt * 16 + (c ^ 1) * 8 + q) * NDIM);
                #pragma unroll
                for (int j = 0; j < 8; ++j) pmv[j] = pmrow2[j * 64 + l];
            } else if (ti + 1 < TILES) {
                const f32x4* pmrow2 = reinterpret_cast<const f32x4*>(
                    pm + ((long)(rt + 1) * 16 + c0 * 8 + q) * NDIM);
                #pragma unroll
                for (int j = 0; j < 8; ++j) pmv[j] = pmrow2[j * 64 + l];
            }

            // Michelot sparsemax, tau0 = max(rowmax-1, (sum-1)/N); in-register
            float s = 0.f, m = zv[0];
            #pragma unroll
            for (int i = 0; i < 32; ++i) { s += zv[i]; m = fmaxf(m, zv[i]); }
            #pragma unroll
            for (int off = 32; off > 0; off >>= 1) {
                s += __shfl_xor(s, off, 64);
                m = fmaxf(m, __shfl_xor(m, off, 64));
            }
            float tau = fmaxf(m - 1.f, (s - 1.f) * (1.f / 2048.f));
            float cprev = -1.f;
            for (int itr = 0; itr < 64; ++itr) {
                float ps = 0.f, pc = 0.f;
                #pragma unroll
                for (int i = 0; i < 32; ++i) {
                    bool a = zv[i] > tau;
                    ps += a ? zv[i] : 0.f;
                    pc += a ? 1.f : 0.f;
                }
                #pragma unroll
                for (int off = 32; off > 0; off >>= 1) {
                    ps += __shfl_xor(ps, off, 64);
                    pc += __shfl_xor(pc, off, 64);
                }
                tau = (ps - 1.f) / pc;          // pc >= 1 always
                if (pc == cprev) break;         // stable count = fixpoint
                cprev = pc;
            }

            // out = max(z - tau, 0), coalesced f32x4
            f32x4* orow = reinterpret_cast<f32x4*>(out + grow * NDIM);
            #pragma unroll
            for (int j = 0; j < 8; ++j) {
                f32x4 v;
                v.x = fmaxf(zv[j * 4 + 0] - tau, 0.f);
                v.y = fmaxf(zv[j * 4 + 1] - tau, 0.f);
                v.z = fmaxf(zv[j * 4 + 2] - tau, 0.f);
                v.w = fmaxf(zv[j * 4 + 3] - tau, 0.f);
                orow[j * 64 + l] = v;
            }
        }
    }
}

// ---------------------------------------------------------------------------
// Fallback (R1 kernel) if d_ws too small.
// ---------------------------------------------------------------------------
__device__ inline float wave_sum(float v) {
    #pragma unroll
    for (int off = 32; off > 0; off >>= 1) v += __shfl_xor(v, off, 64);
    return v;
}

__global__ __launch_bounds__(256)
void fused_sparsemax_fallback(const float* __restrict__ x,
                              const float* __restrict__ pm,
                              const float* __restrict__ W,
                              float* __restrict__ out) {
    __shared__ float xs[8][KDIM];
    __shared__ float zsf[4][NDIM];
    const int tid  = threadIdx.x;
    const int lane = tid & 63;
    const int wv   = tid >> 6;
    const long r0  = (long)blockIdx.x * 8;
    {
        const float4* src = reinterpret_cast<const float4*>(x + r0 * KDIM);
        reinterpret_cast<float4*>(&xs[0][0])[tid] = src[tid];
    }
    __syncthreads();
    float acc[8][8];
    #pragma unroll
    for (int r = 0; r < 8; ++r)
        #pragma unroll
        for (int j = 0; j < 8; ++j) acc[r][j] = 0.f;
    const float4* Wv4 = reinterpret_cast<const float4*>(W);
    #pragma unroll 4
    for (int k = 0; k < KDIM; ++k) {
        const float4 w0 = Wv4[k * (NDIM / 4) + tid];
        const float4 w1 = Wv4[k * (NDIM / 4) + 256 + tid];
        #pragma unroll
        for (int r = 0; r < 8; ++r) {
            const float xv = xs[r][k];
            acc[r][0] = fmaf(xv, w0.x, acc[r][0]);
            acc[r][1] = fmaf(xv, w0.y, acc[r][1]);
            acc[r][2] = fmaf(xv, w0.z, acc[r][2]);
            acc[r][3] = fmaf(xv, w0.w, acc[r][3]);
            acc[r][4] = fmaf(xv, w1.x, acc[r][4]);
            acc[r][5] = fmaf(xv, w1.y, acc[r][5]);
            acc[r][6] = fmaf(xv, w1.z, acc[r][6]);
            acc[r][7] = fmaf(xv, w1.w, acc[r][7]);
        }
    }
    const float4* pmv = reinterpret_cast<const float4*>(pm);
    #pragma unroll
    for (int half = 0; half < 2; ++half) {
        __syncthreads();
        #pragma unroll
        for (int rr = 0; rr < 4; ++rr) {
            const int r = half * 4 + rr;
            const long rowbase4 = (r0 + r) * (NDIM / 4);
            const float4 m0 = pmv[rowbase4 + tid];
            const float4 m1 = pmv[rowbase4 + 256 + tid];
            float4 z0, z1;
            z0.x = acc[r][0] * m0.x; z0.y = acc[r][1] * m0.y;
            z0.z = acc[r][2] * m0.z; z0.w = acc[r][3] * m0.w;
            z1.x = acc[r][4] * m1.x; z1.y = acc[r][5] * m1.y;
            z1.z = acc[r][6] * m1.z; z1.w = acc[r][7] * m1.w;
            float4* zr = reinterpret_cast<float4*>(&zsf[rr][0]);
            zr[tid] = z0; zr[256 + tid] = z1;
        }
        __syncthreads();
        float zvv[32];
        const float4* zr = reinterpret_cast<const float4*>(&zsf[wv][0]);
        #pragma unroll
        for (int cc = 0; cc < 8; ++cc) {
            const float4 v = zr[cc * 64 + lane];
            zvv[cc * 4 + 0] = v.x; zvv[cc * 4 + 1] = v.y;
            zvv[cc * 4 + 2] = v.z; zvv[cc * 4 + 3] = v.w;
        }
        float s = 0.f;
        #pragma unroll
        for (int i = 0; i < 32; ++i) s += zvv[i];
        s = wave_sum(s);
        float tau = (s - 1.f) / 2048.f;
        float cprev = 2048.f;
        for (int itf = 0; itf < 64; ++itf) {
            float ps = 0.f, pc = 0.f;
            #pragma unroll
            for (int i = 0; i < 32; ++i)
                if (zvv[i] > tau) { ps += zvv[i]; pc += 1.f; }
            ps = wave_sum(ps);
            pc = wave_sum(pc);
            tau = (ps - 1.f) / pc;
            if (pc == cprev) break;
            cprev = pc;
        }
        float4* orow = reinterpret_cast<float4*>(out + (r0 + half * 4 + wv) * NDIM);
        #pragma unroll
        for (int cc = 0; cc < 8; ++cc) {
            float4 v;
            v.x = fmaxf(zvv[cc * 4 + 0] - tau, 0.f);
            v.y = fmaxf(zvv[cc * 4 + 1] - tau, 0.f);
            v.z = fmaxf(zvv[cc * 4 + 2] - tau, 0.f);
            v.w = fmaxf(zvv[cc * 4 + 3] - tau, 0.f);
            orow[cc * 64 + lane] = v;
        }
    }
}

extern "C" void kernel_launch(void* const* d_in, const int* in_sizes, int n_in,
                              void* d_out, int out_size, void* d_ws, size_t ws_size,
                              hipStream_t stream) {
    const float* x  = (const float*)d_in[0];   // [32768, 128]
    const float* pm = (const float*)d_in[1];   // [32768, 2048]
    const float* W  = (const float*)d_in[2];   // [128, 2048]
    float* out = (float*)d_out;

    const size_t szA = (size_t)BATCH * KDIM * sizeof(ushort);   // 8 MB each
    const size_t szB = (size_t)KDIM * NDIM * sizeof(ushort);    // 512 KB
    const size_t need = 2 * szA + szB;

    if (ws_size >= need) {
        char* base = (char*)d_ws;
        ushort* Ah = (ushort*)(base);
        ushort* Al = (ushort*)(base + szA);
        ushort* Bh = (ushort*)(base + 2 * szA);

        conv_x_kernel<<<(BATCH * KDIM) / 256, 256, 0, stream>>>(x, Ah, Al);
        conv_w_kernel<<<(KDIM * NDIM) / 256, 256, 0, stream>>>(W, Bh);
        mfma_sparsemax_kernel<<<GRID, 512, LDS_BYTES, stream>>>(Ah, Al, Bh, pm, out);
    } else {
        fused_sparsemax_fallback<<<BATCH / 8, 256, 0, stream>>>(x, pm, W, out);
    }
}

// Round 19
// 204.175 us; speedup vs baseline: 1.6302x; 1.6302x over previous
//
#include <hip/hip_runtime.h>
#include <hip/hip_bf16.h>

constexpr int BATCH = 32768;
constexpr int KDIM  = 128;    // IN_F
constexpr int NDIM  = 2048;   // OUT_F

using f32x4  = __attribute__((ext_vector_type(4))) float;
using bf16x8 = __attribute__((ext_vector_type(8))) short;

// ---------------------------------------------------------------------------
// R19 = exact restore of the R16 champion (203.7 us).
//
// Fragment order for mfma_f32_16x16x32_bf16 (verified R2/R3):
//   A (MxK): lane l holds m = l&15,  k(j) = 4*(l>>4) + (j&3) + 16*(j>>2)
//   B (KxN): lane l holds n = l&15,  same k(j)
//   D:       lane l holds col = l&15, row = (l>>4)*4 + reg
// 2-term split: z = (x_hi + x_lo) @ W_hi  (absmax ~8e-3 < 2e-2 threshold)
//
// Structure: grid 2048, 512 thr (8 waves), 16 rows/block; GEMM in AGPRs; z
// redistributed through 64KB LDS in two 8-row chunks (block-staggered order);
// wave owns one full row: coalesced pm/out, in-register wave-local Michelot
// (tau0 = max(rowmax-1,(sum-1)/N), fixpoint in ~2-4 iters); pm register
// prefetch: entry-issued for first chunk (flies under GEMM), second chunk's
// issued right after the first gather (flies under Michelot+store).
//
// Negative results bracketing this design (kept for the record):
//  - NT stores: +170MB write amplification (R13)
//  - global_load_lds pm staging: bank conflicts + mystery traffic (R13/R15)
//  - persistent blocks: RA spills / +300MB traffic (R4-7, R15)
//  - 1024-thr blocks: RA targets 8 waves/EU -> 64 VGPR -> spills (R5-7)
//  - two-kernel split: z round-trip costs more than fusion saves (R17)
//  - cross-tile pm pipeline: VGPR cap -> spills, WRITE +217MB (R18)
//  - occupancy 2x via register diet: same time (R14) - not the lever
// ---------------------------------------------------------------------------

__device__ inline void split_bf16(float v, ushort& hi, ushort& lo) {
    __hip_bfloat16 h = __float2bfloat16(v);
    float r = v - __bfloat162float(h);
    __hip_bfloat16 l = __float2bfloat16(r);
    hi = *reinterpret_cast<ushort*>(&h);
    lo = *reinterpret_cast<ushort*>(&l);
}

// W [128][2048] -> Bh[nt=128][kk=4][lane=64][j=8]  (hi only)
__global__ __launch_bounds__(256)
void conv_w_kernel(const float* __restrict__ W, ushort* __restrict__ Bh) {
    int id = blockIdx.x * 256 + threadIdx.x;      // 0 .. 262143
    int j  = id & 7;
    int l  = (id >> 3) & 63;
    int kk = (id >> 9) & 3;
    int nt = id >> 11;
    int k  = kk * 32 + 4 * (l >> 4) + (j & 3) + 16 * (j >> 2);
    int n  = nt * 16 + (l & 15);
    __hip_bfloat16 h = __float2bfloat16(W[k * NDIM + n]);
    Bh[id] = *reinterpret_cast<ushort*>(&h);
}

// x [32768][128] -> A{h,l}[rt=2048][kk=4][lane=64][j=8]
__global__ __launch_bounds__(256)
void conv_x_kernel(const float* __restrict__ x,
                   ushort* __restrict__ Ah, ushort* __restrict__ Al) {
    int id = blockIdx.x * 256 + threadIdx.x;      // 0 .. 4194303
    int j  = id & 7;
    int l  = (id >> 3) & 63;
    int kk = (id >> 9) & 3;
    int rt = id >> 11;
    int k  = kk * 32 + 4 * (l >> 4) + (j & 3) + 16 * (j >> 2);
    int m  = rt * 16 + (l & 15);
    ushort hi, lo;
    split_bf16(x[m * KDIM + k], hi, lo);
    Ah[id] = hi; Al[id] = lo;
}

// ---------------------------------------------------------------------------
// Main: grid 2048, 512 thr (8 waves), 16 rows x 2048 cols per block.
// ---------------------------------------------------------------------------
constexpr int GRID = BATCH / 16;                // 2048
constexpr int LDS_BYTES = 8 * NDIM * 4;         // 65536 B

__global__ __launch_bounds__(512, 2)
void mfma_sparsemax_kernel(const ushort* __restrict__ Ah, const ushort* __restrict__ Al,
                           const ushort* __restrict__ Bh,
                           const float* __restrict__ pm, float* __restrict__ out) {
    extern __shared__ float zs[];               // [8][2048]

    const int tid = threadIdx.x;
    const int l   = tid & 63;
    const int q   = tid >> 6;                   // wave id 0..7
    const int g   = l >> 4;
    const int rt  = blockIdx.x;                 // row-tile (16 rows)
    const int c0  = (blockIdx.x >> 8) & 1;      // chunk-order stagger bit

    const bf16x8* A8h = reinterpret_cast<const bf16x8*>(Ah);
    const bf16x8* A8l = reinterpret_cast<const bf16x8*>(Al);
    const bf16x8* B8h = reinterpret_cast<const bf16x8*>(Bh);

    // ---- entry prefetch: pm row for the FIRST-processed chunk (c0*8+q) ----
    f32x4 pmv[8];
    {
        const f32x4* pmrow = reinterpret_cast<const f32x4*>(
            pm + ((long)rt * 16 + c0 * 8 + q) * NDIM);
        #pragma unroll
        for (int j = 0; j < 8; ++j) pmv[j] = pmrow[j * 64 + l];
    }

    // ---- A fragments (16 rows) ----
    bf16x8 ah[4], al[4];
    #pragma unroll
    for (int kk = 0; kk < 4; ++kk) {
        ah[kk] = A8h[(rt * 4 + kk) * 64 + l];
        al[kk] = A8l[(rt * 4 + kk) * 64 + l];
    }

    // ---- GEMM: wave q -> col tiles nt = q*16+t (pm loads fly underneath) ----
    f32x4 acc[16];
    #pragma unroll
    for (int t = 0; t < 16; ++t) {
        const int nt = q * 16 + t;
        f32x4 c = {0.f, 0.f, 0.f, 0.f};
        #pragma unroll
        for (int kk = 0; kk < 4; ++kk) {
            bf16x8 b = B8h[(nt * 4 + kk) * 64 + l];
            c = __builtin_amdgcn_mfma_f32_16x16x32_bf16(ah[kk], b, c, 0, 0, 0);
            c = __builtin_amdgcn_mfma_f32_16x16x32_bf16(al[kk], b, c, 0, 0, 0);
        }
        acc[t] = c;
    }

    // ---- two 8-row chunks through LDS, block-staggered order ----
    #pragma unroll
    for (int cc = 0; cc < 2; ++cc) {
        const int c = cc ^ c0;                  // this block's chunk order
        __syncthreads();                        // zs free (prev chunk consumed)

        // scatter: g-groups 2c,2c+1 hold chunk c's rows (local (g&1)*4+r)
        if ((g >> 1) == c) {
            #pragma unroll
            for (int t = 0; t < 16; ++t)
                #pragma unroll
                for (int r = 0; r < 4; ++r)
                    zs[((g & 1) * 4 + r) * NDIM + q * 256 + t * 16 + (l & 15)] = acc[t][r];
        }

        __syncthreads();                        // zs ready

        // gather my row, gate by (prefetched) pm
        const long grow = (long)rt * 16 + c * 8 + q;
        const f32x4* zrow = reinterpret_cast<const f32x4*>(zs + q * NDIM);
        float zv[32];
        #pragma unroll
        for (int j = 0; j < 8; ++j) {
            f32x4 v = zrow[j * 64 + l];
            zv[j * 4 + 0] = v.x * pmv[j].x;
            zv[j * 4 + 1] = v.y * pmv[j].y;
            zv[j * 4 + 2] = v.z * pmv[j].z;
            zv[j * 4 + 3] = v.w * pmv[j].w;
        }

        // issue NEXT chunk's pm loads now (fly under Michelot + store + scatter)
        if (cc == 0) {
            const f32x4* pmrow2 = reinterpret_cast<const f32x4*>(
                pm + ((long)rt * 16 + (c ^ 1) * 8 + q) * NDIM);
            #pragma unroll
            for (int j = 0; j < 8; ++j) pmv[j] = pmrow2[j * 64 + l];
        }

        // Michelot sparsemax, tau0 = max(rowmax-1, (sum-1)/N); in-register
        float s = 0.f, m = zv[0];
        #pragma unroll
        for (int i = 0; i < 32; ++i) { s += zv[i]; m = fmaxf(m, zv[i]); }
        #pragma unroll
        for (int off = 32; off > 0; off >>= 1) {
            s += __shfl_xor(s, off, 64);
            m = fmaxf(m, __shfl_xor(m, off, 64));
        }
        float tau = fmaxf(m - 1.f, (s - 1.f) * (1.f / 2048.f));
        float cprev = -1.f;
        for (int itr = 0; itr < 64; ++itr) {
            float ps = 0.f, pc = 0.f;
            #pragma unroll
            for (int i = 0; i < 32; ++i) {
                bool a = zv[i] > tau;
                ps += a ? zv[i] : 0.f;
                pc += a ? 1.f : 0.f;
            }
            #pragma unroll
            for (int off = 32; off > 0; off >>= 1) {
                ps += __shfl_xor(ps, off, 64);
                pc += __shfl_xor(pc, off, 64);
            }
            tau = (ps - 1.f) / pc;              // pc >= 1 always
            if (pc == cprev) break;             // stable count = fixpoint
            cprev = pc;
        }

        // out = max(z - tau, 0), coalesced f32x4
        f32x4* orow = reinterpret_cast<f32x4*>(out + grow * NDIM);
        #pragma unroll
        for (int j = 0; j < 8; ++j) {
            f32x4 v;
            v.x = fmaxf(zv[j * 4 + 0] - tau, 0.f);
            v.y = fmaxf(zv[j * 4 + 1] - tau, 0.f);
            v.z = fmaxf(zv[j * 4 + 2] - tau, 0.f);
            v.w = fmaxf(zv[j * 4 + 3] - tau, 0.f);
            orow[j * 64 + l] = v;
        }
    }
}

// ---------------------------------------------------------------------------
// Fallback (R1 kernel) if d_ws too small.
// ---------------------------------------------------------------------------
__device__ inline float wave_sum(float v) {
    #pragma unroll
    for (int off = 32; off > 0; off >>= 1) v += __shfl_xor(v, off, 64);
    return v;
}

__global__ __launch_bounds__(256)
void fused_sparsemax_fallback(const float* __restrict__ x,
                              const float* __restrict__ pm,
                              const float* __restrict__ W,
                              float* __restrict__ out) {
    __shared__ float xs[8][KDIM];
    __shared__ float zsf[4][NDIM];
    const int tid  = threadIdx.x;
    const int lane = tid & 63;
    const int wv   = tid >> 6;
    const long r0  = (long)blockIdx.x * 8;
    {
        const float4* src = reinterpret_cast<const float4*>(x + r0 * KDIM);
        reinterpret_cast<float4*>(&xs[0][0])[tid] = src[tid];
    }
    __syncthreads();
    float acc[8][8];
    #pragma unroll
    for (int r = 0; r < 8; ++r)
        #pragma unroll
        for (int j = 0; j < 8; ++j) acc[r][j] = 0.f;
    const float4* Wv4 = reinterpret_cast<const float4*>(W);
    #pragma unroll 4
    for (int k = 0; k < KDIM; ++k) {
        const float4 w0 = Wv4[k * (NDIM / 4) + tid];
        const float4 w1 = Wv4[k * (NDIM / 4) + 256 + tid];
        #pragma unroll
        for (int r = 0; r < 8; ++r) {
            const float xv = xs[r][k];
            acc[r][0] = fmaf(xv, w0.x, acc[r][0]);
            acc[r][1] = fmaf(xv, w0.y, acc[r][1]);
            acc[r][2] = fmaf(xv, w0.z, acc[r][2]);
            acc[r][3] = fmaf(xv, w0.w, acc[r][3]);
            acc[r][4] = fmaf(xv, w1.x, acc[r][4]);
            acc[r][5] = fmaf(xv, w1.y, acc[r][5]);
            acc[r][6] = fmaf(xv, w1.z, acc[r][6]);
            acc[r][7] = fmaf(xv, w1.w, acc[r][7]);
        }
    }
    const float4* pmv = reinterpret_cast<const float4*>(pm);
    #pragma unroll
    for (int half = 0; half < 2; ++half) {
        __syncthreads();
        #pragma unroll
        for (int rr = 0; rr < 4; ++rr) {
            const int r = half * 4 + rr;
            const long rowbase4 = (r0 + r) * (NDIM / 4);
            const float4 m0 = pmv[rowbase4 + tid];
            const float4 m1 = pmv[rowbase4 + 256 + tid];
            float4 z0, z1;
            z0.x = acc[r][0] * m0.x; z0.y = acc[r][1] * m0.y;
            z0.z = acc[r][2] * m0.z; z0.w = acc[r][3] * m0.w;
            z1.x = acc[r][4] * m1.x; z1.y = acc[r][5] * m1.y;
            z1.z = acc[r][6] * m1.z; z1.w = acc[r][7] * m1.w;
            float4* zr = reinterpret_cast<float4*>(&zsf[rr][0]);
            zr[tid] = z0; zr[256 + tid] = z1;
        }
        __syncthreads();
        float zvv[32];
        const float4* zr = reinterpret_cast<const float4*>(&zsf[wv][0]);
        #pragma unroll
        for (int cc = 0; cc < 8; ++cc) {
            const float4 v = zr[cc * 64 + lane];
            zvv[cc * 4 + 0] = v.x; zvv[cc * 4 + 1] = v.y;
            zvv[cc * 4 + 2] = v.z; zvv[cc * 4 + 3] = v.w;
        }
        float s = 0.f;
        #pragma unroll
        for (int i = 0; i < 32; ++i) s += zvv[i];
        s = wave_sum(s);
        float tau = (s - 1.f) / 2048.f;
        float cprev = 2048.f;
        for (int itf = 0; itf < 64; ++itf) {
            float ps = 0.f, pc = 0.f;
            #pragma unroll
            for (int i = 0; i < 32; ++i)
                if (zvv[i] > tau) { ps += zvv[i]; pc += 1.f; }
            ps = wave_sum(ps);
            pc = wave_sum(pc);
            tau = (ps - 1.f) / pc;
            if (pc == cprev) break;
            cprev = pc;
        }
        float4* orow = reinterpret_cast<float4*>(out + (r0 + half * 4 + wv) * NDIM);
        #pragma unroll
        for (int cc = 0; cc < 8; ++cc) {
            float4 v;
            v.x = fmaxf(zvv[cc * 4 + 0] - tau, 0.f);
            v.y = fmaxf(zvv[cc * 4 + 1] - tau, 0.f);
            v.z = fmaxf(zvv[cc * 4 + 2] - tau, 0.f);
            v.w = fmaxf(zvv[cc * 4 + 3] - tau, 0.f);
            orow[cc * 64 + lane] = v;
        }
    }
}

extern "C" void kernel_launch(void* const* d_in, const int* in_sizes, int n_in,
                              void* d_out, int out_size, void* d_ws, size_t ws_size,
                              hipStream_t stream) {
    const float* x  = (const float*)d_in[0];   // [32768, 128]
    const float* pm = (const float*)d_in[1];   // [32768, 2048]
    const float* W  = (const float*)d_in[2];   // [128, 2048]
    float* out = (float*)d_out;

    const size_t szA = (size_t)BATCH * KDIM * sizeof(ushort);   // 8 MB each
    const size_t szB = (size_t)KDIM * NDIM * sizeof(ushort);    // 512 KB
    const size_t need = 2 * szA + szB;

    if (ws_size >= need) {
        char* base = (char*)d_ws;
        ushort* Ah = (ushort*)(base);
        ushort* Al = (ushort*)(base + szA);
        ushort* Bh = (ushort*)(base + 2 * szA);

        conv_x_kernel<<<(BATCH * KDIM) / 256, 256, 0, stream>>>(x, Ah, Al);
        conv_w_kernel<<<(KDIM * NDIM) / 256, 256, 0, stream>>>(W, Bh);
        mfma_sparsemax_kernel<<<GRID, 512, LDS_BYTES, stream>>>(Ah, Al, Bh, pm, out);
    } else {
        fused_sparsemax_fallback<<<BATCH / 8, 256, 0, stream>>>(x, pm, W, out);
    }
}